// Round 3
// baseline (590.273 us; speedup 1.0000x reference)
//
#include <hip/hip_runtime.h>

// ---------------------------------------------------------------------------
// LSH attention, MI355X.  B=2, S=2048, E=1024, H=16, Dh=64, NB=64, NH=6.
// ALL inputs/outputs are FP32 (reference is jnp.float32 end to end).
//   0) split_kernel: fp32 -> bf16 hi (+ optional bf16 lo residual)
//   1) gemm_q: Q = x @ Wq^T + bq, 3-term hi/lo bf16 MFMA (~1e-5 accurate)
//      -> Qf fp32 [tok,1024] (buckets), Qb/Qlo bf16 [B,H,S,Dh] (QK^T)
//   2) gemm_v: Vt = (x @ Wv^T + bv)^T, 1-term bf16, stored [B,H,Dh,S]
//   3) bucket_kernel: bucket bits = sign(fp32 q . hyperplanes) + row norms^2
//   4) attn_kernel: softmax with PRECOMPUTED upper-bound shift (no online
//      max, no rescale, no in-loop shuffles):  m_row = (63/32)|q_s| M + 0.5,
//      provably >= any logit (Cauchy-Schwarz), so exp never overflows and
//      the final division cancels the common scale.
// Workspace (62.5 MB):
//   xh 8 | xl 8 | Wqh 2 | Wql 2 | Wvh 2 | Qb 8 | Qlo 8 | Vt 8 | Qf 16
//   | bkt .25 | rown .25
// ---------------------------------------------------------------------------

typedef short short8 __attribute__((ext_vector_type(8)));
typedef float f32x4 __attribute__((ext_vector_type(4)));
typedef unsigned short us4 __attribute__((ext_vector_type(4)));

__device__ __forceinline__ float bff(unsigned short h) {
    return __uint_as_float(((unsigned int)h) << 16);
}
__device__ __forceinline__ unsigned short f2bf(float f) {  // RNE, finite inputs
    unsigned int u = __float_as_uint(f);
    u += 0x7fffu + ((u >> 16) & 1u);
    return (unsigned short)(u >> 16);
}

// ---------------------------------------------------------------------------
// fp32 -> bf16 hi (+ lo residual).  float4-vectorized.
// ---------------------------------------------------------------------------
__global__ __launch_bounds__(256) void split_kernel(
    const float* __restrict__ in, unsigned short* __restrict__ hi,
    unsigned short* __restrict__ lo, int n4)
{
    const int idx = blockIdx.x * 256 + threadIdx.x;
    if (idx >= n4) return;
    const float4 v = ((const float4*)in)[idx];
    us4 h;
    h.x = f2bf(v.x); h.y = f2bf(v.y); h.z = f2bf(v.z); h.w = f2bf(v.w);
    ((us4*)hi)[idx] = h;
    if (lo) {
        us4 l;
        l.x = f2bf(v.x - bff(h.x)); l.y = f2bf(v.y - bff(h.y));
        l.z = f2bf(v.z - bff(h.z)); l.w = f2bf(v.w - bff(h.w));
        ((us4*)lo)[idx] = l;
    }
}

// ---------------------------------------------------------------------------
// Q-GEMM: C[m,n] = sum_k x[m,k]*Wq[n,k] + bq[n], 3-term hi/lo split.
// 128x128 tile, 4 waves, wave owns 128x32; frags direct from global (L1/L2).
// ---------------------------------------------------------------------------
__global__ __launch_bounds__(256) void gemm_q(
    const unsigned short* __restrict__ xh, const unsigned short* __restrict__ xl,
    const unsigned short* __restrict__ wh, const unsigned short* __restrict__ wl,
    const float* __restrict__ bias, float* __restrict__ Qf,
    unsigned short* __restrict__ Qb, unsigned short* __restrict__ Qlo)
{
    const int tid = threadIdx.x;
    const int w = tid >> 6, lane = tid & 63;
    const int i = lane & 15, qd = lane >> 4;
    const int m0 = blockIdx.x * 128;
    const int nb = blockIdx.y * 128 + w * 32;

    f32x4 acc[8][2];
#pragma unroll
    for (int a = 0; a < 8; ++a)
#pragma unroll
        for (int b2 = 0; b2 < 2; ++b2) acc[a][b2] = f32x4{0.f, 0.f, 0.f, 0.f};

    const unsigned short* aph = xh + (size_t)(m0 + i) * 1024 + qd * 8;
    const unsigned short* apl = xl + (size_t)(m0 + i) * 1024 + qd * 8;
    const unsigned short* bph = wh + (size_t)(nb + i) * 1024 + qd * 8;
    const unsigned short* bpl = wl + (size_t)(nb + i) * 1024 + qd * 8;

    for (int k0 = 0; k0 < 1024; k0 += 32) {
        short8 ah[8], al[8], bh2[2], bl2[2];
#pragma unroll
        for (int mm = 0; mm < 8; ++mm) {
            ah[mm] = *(const short8*)(aph + (size_t)mm * 16 * 1024 + k0);
            al[mm] = *(const short8*)(apl + (size_t)mm * 16 * 1024 + k0);
        }
#pragma unroll
        for (int nn = 0; nn < 2; ++nn) {
            bh2[nn] = *(const short8*)(bph + (size_t)nn * 16 * 1024 + k0);
            bl2[nn] = *(const short8*)(bpl + (size_t)nn * 16 * 1024 + k0);
        }
#pragma unroll
        for (int mm = 0; mm < 8; ++mm)
#pragma unroll
            for (int nn = 0; nn < 2; ++nn) {
                acc[mm][nn] = __builtin_amdgcn_mfma_f32_16x16x32_bf16(
                    ah[mm], bh2[nn], acc[mm][nn], 0, 0, 0);
                acc[mm][nn] = __builtin_amdgcn_mfma_f32_16x16x32_bf16(
                    al[mm], bh2[nn], acc[mm][nn], 0, 0, 0);
                acc[mm][nn] = __builtin_amdgcn_mfma_f32_16x16x32_bf16(
                    ah[mm], bl2[nn], acc[mm][nn], 0, 0, 0);
            }
    }

    // C layout: col = i (lane&15), row = qd*4 + reg  [m89-verified].
#pragma unroll
    for (int mm = 0; mm < 8; ++mm)
#pragma unroll
        for (int nn = 0; nn < 2; ++nn)
#pragma unroll
            for (int rr = 0; rr < 4; ++rr) {
                const int row = m0 + mm * 16 + qd * 4 + rr;  // token b*2048+s
                const int col = nb + nn * 16 + i;            // channel h*64+d
                const float v = acc[mm][nn][rr] + bias[col];
                Qf[(size_t)row * 1024 + col] = v;
                const unsigned short hs = f2bf(v);
                const float lo = v - bff(hs);
                const int b = row >> 11, s = row & 2047;
                const int hh = col >> 6, d = col & 63;
                const size_t oi = ((size_t)((b << 4) + hh) * 2048 + s) * 64 + d;
                Qb[oi] = hs;
                Qlo[oi] = f2bf(lo);
            }
}

// ---------------------------------------------------------------------------
// V-GEMM (pre-transposed output): A = Wvh [1024 ch, K], B = xh [4096 tok, K];
// C[ch, tok] + bv[ch] -> Vt[b][ch][s].  1-term bf16 (0.3% acc is plenty).
// ---------------------------------------------------------------------------
__global__ __launch_bounds__(256) void gemm_v(
    const unsigned short* __restrict__ wh, const unsigned short* __restrict__ xh,
    const float* __restrict__ bias, unsigned short* __restrict__ Vt)
{
    const int tid = threadIdx.x;
    const int w = tid >> 6, lane = tid & 63;
    const int i = lane & 15, qd = lane >> 4;
    const int m0 = blockIdx.x * 128;           // channel tile
    const int nb = blockIdx.y * 128 + w * 32;  // token tile

    f32x4 acc[8][2];
#pragma unroll
    for (int a = 0; a < 8; ++a)
#pragma unroll
        for (int b2 = 0; b2 < 2; ++b2) acc[a][b2] = f32x4{0.f, 0.f, 0.f, 0.f};

    const unsigned short* ap = wh + (size_t)(m0 + i) * 1024 + qd * 8;
    const unsigned short* bp = xh + (size_t)(nb + i) * 1024 + qd * 8;

    for (int k0 = 0; k0 < 1024; k0 += 32) {
        short8 af[8], bf2[2];
#pragma unroll
        for (int mm = 0; mm < 8; ++mm)
            af[mm] = *(const short8*)(ap + (size_t)mm * 16 * 1024 + k0);
#pragma unroll
        for (int nn = 0; nn < 2; ++nn)
            bf2[nn] = *(const short8*)(bp + (size_t)nn * 16 * 1024 + k0);
#pragma unroll
        for (int mm = 0; mm < 8; ++mm)
#pragma unroll
            for (int nn = 0; nn < 2; ++nn)
                acc[mm][nn] = __builtin_amdgcn_mfma_f32_16x16x32_bf16(
                    af[mm], bf2[nn], acc[mm][nn], 0, 0, 0);
    }

#pragma unroll
    for (int mm = 0; mm < 8; ++mm)
#pragma unroll
        for (int nn = 0; nn < 2; ++nn)
#pragma unroll
            for (int rr = 0; rr < 4; ++rr) {
                const int rch = m0 + mm * 16 + qd * 4 + rr;  // channel h*64+d
                const int tok = nb + nn * 16 + i;            // token b*2048+s
                const float v = acc[mm][nn][rr] + bias[rch];
                const int b = tok >> 11, s = tok & 2047;
                Vt[((size_t)(b * 1024 + rch)) * 2048 + s] = f2bf(v);
            }
}

// ---------------------------------------------------------------------------
// Buckets + row norms from fp32 q.  One thread per (token, head).
// proj_n = sum_d q[d]*hp[d][n] + hp[64][n];  bucket = sum_n (proj_n>=0)<<n;
// rown[bh][s] = |q_row|^2  (for the softmax upper-bound shift).
// ---------------------------------------------------------------------------
__global__ __launch_bounds__(256) void bucket_kernel(
    const float* __restrict__ Qf, const float* __restrict__ hp,
    int* __restrict__ buckets, float* __restrict__ rown)
{
    __shared__ float hpl[65 * 6];
    const int tid = threadIdx.x;
    if (tid < 65 * 6) hpl[tid] = hp[tid];
    __syncthreads();

    const int idx = blockIdx.x * 256 + tid;       // 65536 total
    const int m = idx >> 4, h = idx & 15;
    const float* qrow = Qf + (size_t)m * 1024 + h * 64;

    float pj[6];
    float nrm = 0.f;
#pragma unroll
    for (int n = 0; n < 6; ++n) pj[n] = hpl[64 * 6 + n];
    for (int d = 0; d < 64; ++d) {
        const float qv = qrow[d];
        nrm = fmaf(qv, qv, nrm);
#pragma unroll
        for (int n = 0; n < 6; ++n) pj[n] = fmaf(qv, hpl[d * 6 + n], pj[n]);
    }
    int bkt = 0;
#pragma unroll
    for (int n = 0; n < 6; ++n) bkt |= (pj[n] >= 0.f) << n;
    const int off = ((m >> 11) * 16 + h) * 2048 + (m & 2047);
    buckets[off] = bkt;
    rown[off] = nrm;
}

// ---------------------------------------------------------------------------
// Attention.  Grid (bh=32, qtile=32), bh fastest -> ~4 bh per XCD in L2.
// Block 256 = 4 waves; wave owns 16 q-rows; key tile 64.
// Softmax shift m_row = (63/32)*|q_s|*max|k| + 0.5 is a PRECOMPUTED upper
// bound on every logit of the row -> no online max, no rescale, no in-loop
// cross-lane ops; loop is pure MFMA -> exp -> LDS -> MFMA, fully
// pipelineable (no barriers).  One shuffle-reduce of the sum at epilogue.
// ---------------------------------------------------------------------------
__global__ __launch_bounds__(256, 3) void attn_kernel(
    const unsigned short* __restrict__ Qb, const unsigned short* __restrict__ Qlo,
    const unsigned short* __restrict__ Vt, const int* __restrict__ bks,
    const float* __restrict__ rown, float* __restrict__ out)
{
    __shared__ unsigned short P[4][16 * 64];
    __shared__ float smax[4];

    const int tid = threadIdx.x;
    const int w = tid >> 6, lane = tid & 63;
    const int i = lane & 15, qd = lane >> 4;
    const int bh = blockIdx.x;
    const int q0 = blockIdx.y * 64 + w * 16;

    const unsigned short* Qh = Qb + (size_t)bh * 2048 * 64;
    const unsigned short* Ql = Qlo + (size_t)bh * 2048 * 64;
    const unsigned short* Vb = Vt + (size_t)bh * 64 * 2048;
    const int* bk = bks + bh * 2048;
    const float* rnh = rown + bh * 2048;
    unsigned short* Pw = &P[w][0];

    // ---- prologue: per-(b,h) max key norm, per-row logit upper bound ----
    float lm = 0.f;
    for (int j = tid; j < 2048; j += 256) lm = fmaxf(lm, rnh[j]);
#pragma unroll
    for (int msk = 1; msk < 64; msk <<= 1) lm = fmaxf(lm, __shfl_xor(lm, msk));
    if (lane == 0) smax[w] = lm;
    __syncthreads();
    const float sqM = sqrtf(fmaxf(fmaxf(smax[0], smax[1]),
                                  fmaxf(smax[2], smax[3])));

    float mrow[4];
    int qbr[4];
#pragma unroll
    for (int r = 0; r < 4; ++r) {
        const int row = q0 + qd * 4 + r;
        mrow[r] = 1.96875f * sqrtf(rnh[row]) * sqM + 0.5f;  // >= any logit
        qbr[r] = bk[row];
    }

    // Q A-frags (reused across all key tiles): row = q0+i, k = qd*8 (+32)
    const unsigned short* qp = Qh + (size_t)(q0 + i) * 64 + qd * 8;
    const unsigned short* lp = Ql + (size_t)(q0 + i) * 64 + qd * 8;
    const short8 aqh0 = *(const short8*)qp, aqh1 = *(const short8*)(qp + 32);
    const short8 aql0 = *(const short8*)lp, aql1 = *(const short8*)(lp + 32);

    f32x4 o[4];
#pragma unroll
    for (int d = 0; d < 4; ++d) o[d] = f32x4{0.f, 0.f, 0.f, 0.f};
    float lrun[4] = {0.f, 0.f, 0.f, 0.f};

    for (int t0 = 0; t0 < 2048; t0 += 64) {
        f32x4 s[4];
        int kb[4];
#pragma unroll
        for (int sub = 0; sub < 4; ++sub) {
            const int kr = t0 + sub * 16 + i;
            const unsigned short* kh = Qh + (size_t)kr * 64 + qd * 8;
            const unsigned short* kl = Ql + (size_t)kr * 64 + qd * 8;
            const short8 bh0 = *(const short8*)kh, bh1 = *(const short8*)(kh + 32);
            const short8 bl0 = *(const short8*)kl, bl1 = *(const short8*)(kl + 32);
            f32x4 t = f32x4{0.f, 0.f, 0.f, 0.f};
            t = __builtin_amdgcn_mfma_f32_16x16x32_bf16(aqh0, bh0, t, 0, 0, 0);
            t = __builtin_amdgcn_mfma_f32_16x16x32_bf16(aqh1, bh1, t, 0, 0, 0);
            t = __builtin_amdgcn_mfma_f32_16x16x32_bf16(aql0, bh0, t, 0, 0, 0);
            t = __builtin_amdgcn_mfma_f32_16x16x32_bf16(aql1, bh1, t, 0, 0, 0);
            t = __builtin_amdgcn_mfma_f32_16x16x32_bf16(aqh0, bl0, t, 0, 0, 0);
            t = __builtin_amdgcn_mfma_f32_16x16x32_bf16(aqh1, bl1, t, 0, 0, 0);
            s[sub] = t;
            kb[sub] = bk[t0 + sub * 16 + i];
        }

        // p = exp(logit - m_row); logit = s * (c/32);  c in {62,63}.
        // No max, no rescale: m_row is a fixed upper bound.
#pragma unroll
        for (int sub = 0; sub < 4; ++sub)
#pragma unroll
            for (int r = 0; r < 4; ++r) {
                const float c = (kb[sub] == qbr[r]) ? 1.96875f : 1.9375f;
                const float p = __expf(fmaf(s[sub][r], c, -mrow[r]));
                lrun[r] += p;
                const int row = qd * 4 + r, col = sub * 16 + i;
                Pw[row * 64 + (((col >> 3) ^ (row & 7)) << 3) + (col & 7)] =
                    f2bf(p);
            }

        // A-frag of P: row = i, k-granules qd and qd+4 (wave-local, no barrier)
        const short8 pa0 = *(const short8*)&Pw[i * 64 + ((qd ^ (i & 7)) << 3)];
        const short8 pa1 = *(const short8*)&Pw[i * 64 + (((qd + 4) ^ (i & 7)) << 3)];

#pragma unroll
        for (int dsub = 0; dsub < 4; ++dsub) {
            const unsigned short* vp =
                Vb + (size_t)(dsub * 16 + i) * 2048 + t0 + qd * 8;
            const short8 vb0 = *(const short8*)vp;
            const short8 vb1 = *(const short8*)(vp + 32);
            o[dsub] = __builtin_amdgcn_mfma_f32_16x16x32_bf16(pa0, vb0, o[dsub], 0, 0, 0);
            o[dsub] = __builtin_amdgcn_mfma_f32_16x16x32_bf16(pa1, vb1, o[dsub], 0, 0, 0);
        }
    }

    // Epilogue: reduce the row sums across the 16-lane col groups, then write
    // out[b][s][h*64+d] fp32; s = q0+qd*4+r, d = dsub*16+i.
#pragma unroll
    for (int r = 0; r < 4; ++r) {
#pragma unroll
        for (int msk = 1; msk < 16; msk <<= 1)
            lrun[r] += __shfl_xor(lrun[r], msk);
    }
    const int b = bh >> 4, h = bh & 15;
#pragma unroll
    for (int dsub = 0; dsub < 4; ++dsub)
#pragma unroll
        for (int r = 0; r < 4; ++r) {
            const float v = o[dsub][r] / lrun[r];
            const int srow = q0 + qd * 4 + r;
            out[((size_t)(b * 2048 + srow)) * 1024 + h * 64 + dsub * 16 + i] = v;
        }
}

// ---------------------------------------------------------------------------
extern "C" void kernel_launch(void* const* d_in, const int* in_sizes, int n_in,
                              void* d_out, int out_size, void* d_ws, size_t ws_size,
                              hipStream_t stream)
{
    const float* x  = (const float*)d_in[0];
    const float* Wq = (const float*)d_in[1];
    const float* bq = (const float*)d_in[2];
    const float* Wv = (const float*)d_in[3];
    const float* bv = (const float*)d_in[4];
    const float* hp = (const float*)d_in[5];
    float* out = (float*)d_out;

    char* ws = (char*)d_ws;
    const size_t MB = (size_t)1 << 20;
    unsigned short* xh  = (unsigned short*)(ws);            // 8 MB
    unsigned short* xl  = (unsigned short*)(ws + 8 * MB);   // 8 MB
    unsigned short* Wqh = (unsigned short*)(ws + 16 * MB);  // 2 MB
    unsigned short* Wql = (unsigned short*)(ws + 18 * MB);  // 2 MB
    unsigned short* Wvh = (unsigned short*)(ws + 20 * MB);  // 2 MB
    unsigned short* Qb  = (unsigned short*)(ws + 22 * MB);  // 8 MB
    unsigned short* Qlo = (unsigned short*)(ws + 30 * MB);  // 8 MB
    unsigned short* Vt  = (unsigned short*)(ws + 38 * MB);  // 8 MB
    float*          Qf  = (float*)(ws + 46 * MB);           // 16 MB
    int*        buckets = (int*)(ws + 62 * MB);             // 256 KB
    float*         rown = (float*)(ws + 62 * MB + 256 * 1024);  // 256 KB

    split_kernel<<<dim3(4096), 256, 0, stream>>>(x, xh, xl, 1048576);
    split_kernel<<<dim3(1024), 256, 0, stream>>>(Wq, Wqh, Wql, 262144);
    split_kernel<<<dim3(1024), 256, 0, stream>>>(Wv, Wvh, nullptr, 262144);

    gemm_q<<<dim3(32, 8), 256, 0, stream>>>(xh, xl, Wqh, Wql, bq, Qf, Qb, Qlo);
    gemm_v<<<dim3(8, 32), 256, 0, stream>>>(Wvh, xh, bv, Vt);
    bucket_kernel<<<dim3(256), 256, 0, stream>>>(Qf, hp, buckets, rown);
    attn_kernel<<<dim3(32, 32), 256, 0, stream>>>(Qb, Qlo, Vt, buckets, rown, out);
}

// Round 4
// 333.005 us; speedup vs baseline: 1.7726x; 1.7726x over previous
//
#include <hip/hip_runtime.h>

// ---------------------------------------------------------------------------
// LSH attention, MI355X.  B=2, S=2048, E=1024, H=16, Dh=64, NB=64, NH=6.
// ALL inputs/outputs are FP32 (reference is jnp.float32 end to end).
//   0) split_kernel: fp32 -> bf16 hi (+ optional bf16 lo residual)
//   1) gemm_q: Q = x @ Wq^T + bq, 3-term hi/lo bf16 MFMA (~1e-5 accurate)
//      -> Qf fp32 [tok,1024] (buckets), Qb/Qlo bf16 [B,H,S,Dh] (QK^T)
//   2) gemm_v: Vt = (x @ Wv^T + bv)^T, 1-term bf16, stored [B,H,Dh,S]
//   3) bucket_kernel: bucket bits = sign(fp32 q . hyperplanes) + row norms^2
//   4) attn_kernel v3: K/V tiles staged to LDS via global_load_lds width=16
//      (coalesced, shared by 4 waves) with XOR-swizzle applied on the GLOBAL
//      source side (LDS dest is hardwired base+lane*16); fragments read from
//      LDS conflict-lite; wave owns 32 q-rows; fixed upper-bound softmax
//      shift (no online max).  Round-3 evidence: old version was bound on
//      uncoalesced cache-line transactions (28 loads x 64 lines/wave-iter
//      ~= 917k cyc/CU ~= measured 363us).
// ---------------------------------------------------------------------------

typedef short short8 __attribute__((ext_vector_type(8)));
typedef float f32x4 __attribute__((ext_vector_type(4)));
typedef unsigned short us4 __attribute__((ext_vector_type(4)));

__device__ __forceinline__ float bff(unsigned short h) {
    return __uint_as_float(((unsigned int)h) << 16);
}
__device__ __forceinline__ unsigned short f2bf(float f) {  // RNE, finite inputs
    unsigned int u = __float_as_uint(f);
    u += 0x7fffu + ((u >> 16) & 1u);
    return (unsigned short)(u >> 16);
}

__device__ __forceinline__ void glds16(const unsigned short* g, unsigned short* l) {
    __builtin_amdgcn_global_load_lds(
        (const __attribute__((address_space(1))) unsigned int*)g,
        (__attribute__((address_space(3))) unsigned int*)l, 16, 0, 0);
}

// ---------------------------------------------------------------------------
// fp32 -> bf16 hi (+ lo residual).  float4-vectorized.
// ---------------------------------------------------------------------------
__global__ __launch_bounds__(256) void split_kernel(
    const float* __restrict__ in, unsigned short* __restrict__ hi,
    unsigned short* __restrict__ lo, int n4)
{
    const int idx = blockIdx.x * 256 + threadIdx.x;
    if (idx >= n4) return;
    const float4 v = ((const float4*)in)[idx];
    us4 h;
    h.x = f2bf(v.x); h.y = f2bf(v.y); h.z = f2bf(v.z); h.w = f2bf(v.w);
    ((us4*)hi)[idx] = h;
    if (lo) {
        us4 l;
        l.x = f2bf(v.x - bff(h.x)); l.y = f2bf(v.y - bff(h.y));
        l.z = f2bf(v.z - bff(h.z)); l.w = f2bf(v.w - bff(h.w));
        ((us4*)lo)[idx] = l;
    }
}

// ---------------------------------------------------------------------------
// Q-GEMM: C[m,n] = sum_k x[m,k]*Wq[n,k] + bq[n], 3-term hi/lo split.
// ---------------------------------------------------------------------------
__global__ __launch_bounds__(256) void gemm_q(
    const unsigned short* __restrict__ xh, const unsigned short* __restrict__ xl,
    const unsigned short* __restrict__ wh, const unsigned short* __restrict__ wl,
    const float* __restrict__ bias, float* __restrict__ Qf,
    unsigned short* __restrict__ Qb, unsigned short* __restrict__ Qlo)
{
    const int tid = threadIdx.x;
    const int w = tid >> 6, lane = tid & 63;
    const int i = lane & 15, qd = lane >> 4;
    const int m0 = blockIdx.x * 128;
    const int nb = blockIdx.y * 128 + w * 32;

    f32x4 acc[8][2];
#pragma unroll
    for (int a = 0; a < 8; ++a)
#pragma unroll
        for (int b2 = 0; b2 < 2; ++b2) acc[a][b2] = f32x4{0.f, 0.f, 0.f, 0.f};

    const unsigned short* aph = xh + (size_t)(m0 + i) * 1024 + qd * 8;
    const unsigned short* apl = xl + (size_t)(m0 + i) * 1024 + qd * 8;
    const unsigned short* bph = wh + (size_t)(nb + i) * 1024 + qd * 8;
    const unsigned short* bpl = wl + (size_t)(nb + i) * 1024 + qd * 8;

    for (int k0 = 0; k0 < 1024; k0 += 32) {
        short8 ah[8], al[8], bh2[2], bl2[2];
#pragma unroll
        for (int mm = 0; mm < 8; ++mm) {
            ah[mm] = *(const short8*)(aph + (size_t)mm * 16 * 1024 + k0);
            al[mm] = *(const short8*)(apl + (size_t)mm * 16 * 1024 + k0);
        }
#pragma unroll
        for (int nn = 0; nn < 2; ++nn) {
            bh2[nn] = *(const short8*)(bph + (size_t)nn * 16 * 1024 + k0);
            bl2[nn] = *(const short8*)(bpl + (size_t)nn * 16 * 1024 + k0);
        }
#pragma unroll
        for (int mm = 0; mm < 8; ++mm)
#pragma unroll
            for (int nn = 0; nn < 2; ++nn) {
                acc[mm][nn] = __builtin_amdgcn_mfma_f32_16x16x32_bf16(
                    ah[mm], bh2[nn], acc[mm][nn], 0, 0, 0);
                acc[mm][nn] = __builtin_amdgcn_mfma_f32_16x16x32_bf16(
                    al[mm], bh2[nn], acc[mm][nn], 0, 0, 0);
                acc[mm][nn] = __builtin_amdgcn_mfma_f32_16x16x32_bf16(
                    ah[mm], bl2[nn], acc[mm][nn], 0, 0, 0);
            }
    }

#pragma unroll
    for (int mm = 0; mm < 8; ++mm)
#pragma unroll
        for (int nn = 0; nn < 2; ++nn)
#pragma unroll
            for (int rr = 0; rr < 4; ++rr) {
                const int row = m0 + mm * 16 + qd * 4 + rr;  // token b*2048+s
                const int col = nb + nn * 16 + i;            // channel h*64+d
                const float v = acc[mm][nn][rr] + bias[col];
                Qf[(size_t)row * 1024 + col] = v;
                const unsigned short hs = f2bf(v);
                const float lo = v - bff(hs);
                const int b = row >> 11, s = row & 2047;
                const int hh = col >> 6, d = col & 63;
                const size_t oi = ((size_t)((b << 4) + hh) * 2048 + s) * 64 + d;
                Qb[oi] = hs;
                Qlo[oi] = f2bf(lo);
            }
}

// ---------------------------------------------------------------------------
// V-GEMM (pre-transposed output): A = Wvh [1024 ch, K], B = xh [4096 tok, K];
// C[ch, tok] + bv[ch] -> Vt[b][ch][s].  1-term bf16.
// ---------------------------------------------------------------------------
__global__ __launch_bounds__(256) void gemm_v(
    const unsigned short* __restrict__ wh, const unsigned short* __restrict__ xh,
    const float* __restrict__ bias, unsigned short* __restrict__ Vt)
{
    const int tid = threadIdx.x;
    const int w = tid >> 6, lane = tid & 63;
    const int i = lane & 15, qd = lane >> 4;
    const int m0 = blockIdx.x * 128;           // channel tile
    const int nb = blockIdx.y * 128 + w * 32;  // token tile

    f32x4 acc[8][2];
#pragma unroll
    for (int a = 0; a < 8; ++a)
#pragma unroll
        for (int b2 = 0; b2 < 2; ++b2) acc[a][b2] = f32x4{0.f, 0.f, 0.f, 0.f};

    const unsigned short* ap = wh + (size_t)(m0 + i) * 1024 + qd * 8;
    const unsigned short* bp = xh + (size_t)(nb + i) * 1024 + qd * 8;

    for (int k0 = 0; k0 < 1024; k0 += 32) {
        short8 af[8], bf2[2];
#pragma unroll
        for (int mm = 0; mm < 8; ++mm)
            af[mm] = *(const short8*)(ap + (size_t)mm * 16 * 1024 + k0);
#pragma unroll
        for (int nn = 0; nn < 2; ++nn)
            bf2[nn] = *(const short8*)(bp + (size_t)nn * 16 * 1024 + k0);
#pragma unroll
        for (int mm = 0; mm < 8; ++mm)
#pragma unroll
            for (int nn = 0; nn < 2; ++nn)
                acc[mm][nn] = __builtin_amdgcn_mfma_f32_16x16x32_bf16(
                    af[mm], bf2[nn], acc[mm][nn], 0, 0, 0);
    }

#pragma unroll
    for (int mm = 0; mm < 8; ++mm)
#pragma unroll
        for (int nn = 0; nn < 2; ++nn)
#pragma unroll
            for (int rr = 0; rr < 4; ++rr) {
                const int rch = m0 + mm * 16 + qd * 4 + rr;  // channel h*64+d
                const int tok = nb + nn * 16 + i;            // token b*2048+s
                const float v = acc[mm][nn][rr] + bias[rch];
                const int b = tok >> 11, s = tok & 2047;
                Vt[((size_t)(b * 1024 + rch)) * 2048 + s] = f2bf(v);
            }
}

// ---------------------------------------------------------------------------
// Buckets + row norms from fp32 q.  One thread per (token, head).
// ---------------------------------------------------------------------------
__global__ __launch_bounds__(256) void bucket_kernel(
    const float* __restrict__ Qf, const float* __restrict__ hp,
    int* __restrict__ buckets, float* __restrict__ rown)
{
    __shared__ float hpl[65 * 6];
    const int tid = threadIdx.x;
    if (tid < 65 * 6) hpl[tid] = hp[tid];
    __syncthreads();

    const int idx = blockIdx.x * 256 + tid;       // 65536 total
    const int m = idx >> 4, h = idx & 15;
    const float* qrow = Qf + (size_t)m * 1024 + h * 64;

    float pj[6];
    float nrm = 0.f;
#pragma unroll
    for (int n = 0; n < 6; ++n) pj[n] = hpl[64 * 6 + n];
    for (int d = 0; d < 64; ++d) {
        const float qv = qrow[d];
        nrm = fmaf(qv, qv, nrm);
#pragma unroll
        for (int n = 0; n < 6; ++n) pj[n] = fmaf(qv, hpl[d * 6 + n], pj[n]);
    }
    int bkt = 0;
#pragma unroll
    for (int n = 0; n < 6; ++n) bkt |= (pj[n] >= 0.f) << n;
    const int off = ((m >> 11) * 16 + h) * 2048 + (m & 2047);
    buckets[off] = bkt;
    rown[off] = nrm;
}

// ---------------------------------------------------------------------------
// Attention v3.  Grid (bh=32, qtile=16); block 256 = 4 waves; wave owns 32
// q-rows (2 m-subtiles); key tile 64.  Per tile: cooperative LDS staging of
// Khi/Klo/V (24 KB) via global_load_lds(16B) -- global source is XOR-swizzled
// (chunk j of row r fetched from global chunk j^(r&7)) so LDS fragment reads
// land 16B-granule-balanced.  m97-style 2-barrier loop.  LDS 40 KB/block.
// ---------------------------------------------------------------------------
__global__ __launch_bounds__(256, 2) void attn_kernel(
    const unsigned short* __restrict__ Qb, const unsigned short* __restrict__ Qlo,
    const unsigned short* __restrict__ Vt, const int* __restrict__ bks,
    const float* __restrict__ rown, float* __restrict__ out)
{
    __shared__ unsigned short Khi[64 * 64];
    __shared__ unsigned short Klo[64 * 64];
    __shared__ unsigned short Vs[64 * 64];
    __shared__ unsigned short P[4][2][16 * 64];
    __shared__ float smax[4];

    const int tid = threadIdx.x;
    const int w = tid >> 6, lane = tid & 63;
    const int i = lane & 15, qd = lane >> 4;
    const int l8 = lane >> 3, j = lane & 7;
    const int bh = blockIdx.x;
    const int qbase = blockIdx.y * 128 + w * 32;

    const unsigned short* Qh = Qb + (size_t)bh * 2048 * 64;
    const unsigned short* Ql = Qlo + (size_t)bh * 2048 * 64;
    const unsigned short* Vb = Vt + (size_t)bh * 64 * 2048;
    const int* bk = bks + bh * 2048;
    const float* rnh = rown + bh * 2048;

    // ---- prologue: per-(b,h) max key norm -> per-row logit upper bound ----
    float lm = 0.f;
    for (int t = tid; t < 2048; t += 256) lm = fmaxf(lm, rnh[t]);
#pragma unroll
    for (int msk = 1; msk < 64; msk <<= 1) lm = fmaxf(lm, __shfl_xor(lm, msk));
    if (lane == 0) smax[w] = lm;
    __syncthreads();
    const float sqM = sqrtf(fmaxf(fmaxf(smax[0], smax[1]),
                                  fmaxf(smax[2], smax[3])));

    float mrow[2][4], lrun[2][4];
    int qbr[2][4];
#pragma unroll
    for (int ms = 0; ms < 2; ++ms)
#pragma unroll
        for (int r = 0; r < 4; ++r) {
            const int row = qbase + ms * 16 + qd * 4 + r;
            mrow[ms][r] = 1.96875f * sqrtf(rnh[row]) * sqM + 0.5f;
            qbr[ms][r] = bk[row];
            lrun[ms][r] = 0.f;
        }

    // Q A-frags, per m-subtile: row = qbase + ms*16 + i, k = qd*8 (+32)
    short8 aqh0[2], aqh1[2], aql0[2], aql1[2];
#pragma unroll
    for (int ms = 0; ms < 2; ++ms) {
        const unsigned short* qp = Qh + (size_t)(qbase + ms * 16 + i) * 64 + qd * 8;
        const unsigned short* lp = Ql + (size_t)(qbase + ms * 16 + i) * 64 + qd * 8;
        aqh0[ms] = *(const short8*)qp; aqh1[ms] = *(const short8*)(qp + 32);
        aql0[ms] = *(const short8*)lp; aql1[ms] = *(const short8*)(lp + 32);
    }

    f32x4 o[2][4];
#pragma unroll
    for (int ms = 0; ms < 2; ++ms)
#pragma unroll
        for (int d = 0; d < 4; ++d) o[ms][d] = f32x4{0.f, 0.f, 0.f, 0.f};

    for (int t0 = 0; t0 < 2048; t0 += 64) {
        __syncthreads();  // prior tile consumers done
        // ---- stage Khi/Klo/V (8 KB each): wave w stages rows w*16..w*16+15;
        //      LDS chunk j of row r <- global chunk j^(r&7)  (r&7 == l8) ----
#pragma unroll
        for (int c2 = 0; c2 < 2; ++c2) {
            const int r = w * 16 + c2 * 8 + l8;
            const int swz = ((j ^ l8) << 3);
            glds16(Qh + (size_t)(t0 + r) * 64 + swz, &Khi[w * 1024 + c2 * 512]);
            glds16(Ql + (size_t)(t0 + r) * 64 + swz, &Klo[w * 1024 + c2 * 512]);
            glds16(Vb + (size_t)r * 2048 + t0 + swz, &Vs[w * 1024 + c2 * 512]);
        }
        __syncthreads();  // staging visible (compiler drains vmcnt here)

        // ---- QK^T: 4 key-subtiles x (hi/lo 6 MFMAs) x 2 m-subtiles ----
        f32x4 s[2][4];
        int kb[4];
#pragma unroll
        for (int sub = 0; sub < 4; ++sub) {
            const int kr = sub * 16 + i;
            const int sw = i & 7;
            const short8 bh0 = *(const short8*)&Khi[kr * 64 + ((qd ^ sw) << 3)];
            const short8 bh1 = *(const short8*)&Khi[kr * 64 + (((qd + 4) ^ sw) << 3)];
            const short8 bl0 = *(const short8*)&Klo[kr * 64 + ((qd ^ sw) << 3)];
            const short8 bl1 = *(const short8*)&Klo[kr * 64 + (((qd + 4) ^ sw) << 3)];
            kb[sub] = bk[t0 + kr];
#pragma unroll
            for (int ms = 0; ms < 2; ++ms) {
                f32x4 t = f32x4{0.f, 0.f, 0.f, 0.f};
                t = __builtin_amdgcn_mfma_f32_16x16x32_bf16(aqh0[ms], bh0, t, 0, 0, 0);
                t = __builtin_amdgcn_mfma_f32_16x16x32_bf16(aqh1[ms], bh1, t, 0, 0, 0);
                t = __builtin_amdgcn_mfma_f32_16x16x32_bf16(aql0[ms], bh0, t, 0, 0, 0);
                t = __builtin_amdgcn_mfma_f32_16x16x32_bf16(aql1[ms], bh1, t, 0, 0, 0);
                t = __builtin_amdgcn_mfma_f32_16x16x32_bf16(aqh0[ms], bl0, t, 0, 0, 0);
                t = __builtin_amdgcn_mfma_f32_16x16x32_bf16(aqh1[ms], bl1, t, 0, 0, 0);
                s[ms][sub] = t;
            }
        }

        // ---- V B-frags (shared across both m-subtiles) ----
        short8 vb0[4], vb1[4];
#pragma unroll
        for (int dsub = 0; dsub < 4; ++dsub) {
            const int dr = dsub * 16 + i;
            const int sw = i & 7;
            vb0[dsub] = *(const short8*)&Vs[dr * 64 + ((qd ^ sw) << 3)];
            vb1[dsub] = *(const short8*)&Vs[dr * 64 + (((qd + 4) ^ sw) << 3)];
        }

        // ---- exp (fixed upper-bound shift) -> P (LDS) -> PV ----
#pragma unroll
        for (int ms = 0; ms < 2; ++ms) {
            unsigned short* Pw = &P[w][ms][0];
#pragma unroll
            for (int sub = 0; sub < 4; ++sub)
#pragma unroll
                for (int r = 0; r < 4; ++r) {
                    const float c = (kb[sub] == qbr[ms][r]) ? 1.96875f : 1.9375f;
                    const float p = __expf(fmaf(s[ms][sub][r], c, -mrow[ms][r]));
                    lrun[ms][r] += p;
                    const int row = qd * 4 + r, col = sub * 16 + i;
                    Pw[row * 64 + (((col >> 3) ^ (row & 7)) << 3) + (col & 7)] =
                        f2bf(p);
                }
            const short8 pa0 = *(const short8*)&Pw[i * 64 + ((qd ^ (i & 7)) << 3)];
            const short8 pa1 = *(const short8*)&Pw[i * 64 + (((qd + 4) ^ (i & 7)) << 3)];
#pragma unroll
            for (int dsub = 0; dsub < 4; ++dsub) {
                o[ms][dsub] = __builtin_amdgcn_mfma_f32_16x16x32_bf16(
                    pa0, vb0[dsub], o[ms][dsub], 0, 0, 0);
                o[ms][dsub] = __builtin_amdgcn_mfma_f32_16x16x32_bf16(
                    pa1, vb1[dsub], o[ms][dsub], 0, 0, 0);
            }
        }
    }

    // ---- epilogue: reduce row sums over 16-lane col groups, write fp32 ----
#pragma unroll
    for (int ms = 0; ms < 2; ++ms)
#pragma unroll
        for (int r = 0; r < 4; ++r) {
#pragma unroll
            for (int msk = 1; msk < 16; msk <<= 1)
                lrun[ms][r] += __shfl_xor(lrun[ms][r], msk);
        }
    const int b = bh >> 4, h = bh & 15;
#pragma unroll
    for (int ms = 0; ms < 2; ++ms)
#pragma unroll
        for (int dsub = 0; dsub < 4; ++dsub)
#pragma unroll
            for (int r = 0; r < 4; ++r) {
                const float v = o[ms][dsub][r] / lrun[ms][r];
                const int srow = qbase + ms * 16 + qd * 4 + r;
                out[((size_t)(b * 2048 + srow)) * 1024 + h * 64 + dsub * 16 + i] = v;
            }
}

// ---------------------------------------------------------------------------
extern "C" void kernel_launch(void* const* d_in, const int* in_sizes, int n_in,
                              void* d_out, int out_size, void* d_ws, size_t ws_size,
                              hipStream_t stream)
{
    const float* x  = (const float*)d_in[0];
    const float* Wq = (const float*)d_in[1];
    const float* bq = (const float*)d_in[2];
    const float* Wv = (const float*)d_in[3];
    const float* bv = (const float*)d_in[4];
    const float* hp = (const float*)d_in[5];
    float* out = (float*)d_out;

    char* ws = (char*)d_ws;
    const size_t MB = (size_t)1 << 20;
    unsigned short* xh  = (unsigned short*)(ws);            // 8 MB
    unsigned short* xl  = (unsigned short*)(ws + 8 * MB);   // 8 MB
    unsigned short* Wqh = (unsigned short*)(ws + 16 * MB);  // 2 MB
    unsigned short* Wql = (unsigned short*)(ws + 18 * MB);  // 2 MB
    unsigned short* Wvh = (unsigned short*)(ws + 20 * MB);  // 2 MB
    unsigned short* Qb  = (unsigned short*)(ws + 22 * MB);  // 8 MB
    unsigned short* Qlo = (unsigned short*)(ws + 30 * MB);  // 8 MB
    unsigned short* Vt  = (unsigned short*)(ws + 38 * MB);  // 8 MB
    float*          Qf  = (float*)(ws + 46 * MB);           // 16 MB
    int*        buckets = (int*)(ws + 62 * MB);             // 256 KB
    float*         rown = (float*)(ws + 62 * MB + 256 * 1024);  // 256 KB

    split_kernel<<<dim3(4096), 256, 0, stream>>>(x, xh, xl, 1048576);
    split_kernel<<<dim3(1024), 256, 0, stream>>>(Wq, Wqh, Wql, 262144);
    split_kernel<<<dim3(1024), 256, 0, stream>>>(Wv, Wvh, nullptr, 262144);

    gemm_q<<<dim3(32, 8), 256, 0, stream>>>(xh, xl, Wqh, Wql, bq, Qf, Qb, Qlo);
    gemm_v<<<dim3(8, 32), 256, 0, stream>>>(Wvh, xh, bv, Vt);
    bucket_kernel<<<dim3(256), 256, 0, stream>>>(Qf, hp, buckets, rown);
    attn_kernel<<<dim3(32, 16), 256, 0, stream>>>(Qb, Qlo, Vt, buckets, rown, out);
}

// Round 5
// 235.813 us; speedup vs baseline: 2.5031x; 1.4122x over previous
//
#include <hip/hip_runtime.h>

// ---------------------------------------------------------------------------
// LSH attention, MI355X.  B=2, S=2048, E=1024, H=16, Dh=64, NB=64, NH=6.
// ALL inputs/outputs are FP32 (reference is jnp.float32 end to end).
//   0) split_kernel: fp32 -> bf16 hi (+ optional bf16 lo residual)
//   1) gemm_q: Q = x @ Wq^T + bq, 3-term hi/lo bf16 MFMA (~1e-5 accurate),
//      LDS-staged (v2): global_load_lds(16B) + global-side XOR swizzle.
//   2) gemm_v: Vt = (x @ Wv^T + bv)^T, 1-term bf16, LDS-staged, [B,H,Dh,S]
//   3) bucket_kernel: bucket bits = sign(fp32 q . hyperplanes) + row norms^2
//   4) attn_kernel v3: LDS-staged K/V, fixed upper-bound softmax shift.
// Round-4 evidence: direct-global MFMA fragments (2048B lane stride) cost
// 64 cache lines/load -> gemm_q was transaction-bound at 108us (MfmaUtil 9%).
// Same fix as attn round 4: stage through LDS, swizzle on the global side.
// ---------------------------------------------------------------------------

typedef short short8 __attribute__((ext_vector_type(8)));
typedef float f32x4 __attribute__((ext_vector_type(4)));
typedef unsigned short us4 __attribute__((ext_vector_type(4)));

__device__ __forceinline__ float bff(unsigned short h) {
    return __uint_as_float(((unsigned int)h) << 16);
}
__device__ __forceinline__ unsigned short f2bf(float f) {  // RNE, finite inputs
    unsigned int u = __float_as_uint(f);
    u += 0x7fffu + ((u >> 16) & 1u);
    return (unsigned short)(u >> 16);
}

__device__ __forceinline__ void glds16(const unsigned short* g, unsigned short* l) {
    __builtin_amdgcn_global_load_lds(
        (const __attribute__((address_space(1))) unsigned int*)g,
        (__attribute__((address_space(3))) unsigned int*)l, 16, 0, 0);
}

// ---------------------------------------------------------------------------
// fp32 -> bf16 hi (+ lo residual).  float4-vectorized.
// ---------------------------------------------------------------------------
__global__ __launch_bounds__(256) void split_kernel(
    const float* __restrict__ in, unsigned short* __restrict__ hi,
    unsigned short* __restrict__ lo, int n4)
{
    const int idx = blockIdx.x * 256 + threadIdx.x;
    if (idx >= n4) return;
    const float4 v = ((const float4*)in)[idx];
    us4 h;
    h.x = f2bf(v.x); h.y = f2bf(v.y); h.z = f2bf(v.z); h.w = f2bf(v.w);
    ((us4*)hi)[idx] = h;
    if (lo) {
        us4 l;
        l.x = f2bf(v.x - bff(h.x)); l.y = f2bf(v.y - bff(h.y));
        l.z = f2bf(v.z - bff(h.z)); l.w = f2bf(v.w - bff(h.w));
        ((us4*)lo)[idx] = l;
    }
}

// ---------------------------------------------------------------------------
// Q-GEMM v2 (LDS-staged): C[m,n] = sum_k x[m,k]*Wq[n,k] + bq[n], 3-term.
// 128x128 tile, BK=64; LDS 64 KB (Ah/Al/Bh/Bl 16 KB each).  Staging: wave w
// covers rows w*32..w*32+31 of each array; LDS chunk j of row r holds global
// chunk j^(r&7); fragment reads apply the inverse -> 2-way conflicts (free).
// ---------------------------------------------------------------------------
__global__ __launch_bounds__(256, 1) void gemm_q(
    const unsigned short* __restrict__ xh, const unsigned short* __restrict__ xl,
    const unsigned short* __restrict__ wh, const unsigned short* __restrict__ wl,
    const float* __restrict__ bias, float* __restrict__ Qf,
    unsigned short* __restrict__ Qb, unsigned short* __restrict__ Qlo)
{
    __shared__ unsigned short Ah[128 * 64], Al[128 * 64];
    __shared__ unsigned short Bh[128 * 64], Bl[128 * 64];

    const int tid = threadIdx.x;
    const int w = tid >> 6, lane = tid & 63;
    const int i = lane & 15, qd = lane >> 4;
    const int l8 = lane >> 3, j = lane & 7;
    const int m0 = blockIdx.x * 128;
    const int n0 = blockIdx.y * 128;
    const int nw = w * 32;

    f32x4 acc[8][2];
#pragma unroll
    for (int a = 0; a < 8; ++a)
#pragma unroll
        for (int b2 = 0; b2 < 2; ++b2) acc[a][b2] = f32x4{0.f, 0.f, 0.f, 0.f};

    for (int k0 = 0; k0 < 1024; k0 += 64) {
        __syncthreads();  // prior tile consumers done
        const int gro = ((j ^ l8) << 3);  // swizzled global chunk offset
#pragma unroll
        for (int c = 0; c < 4; ++c) {
            const int r = w * 32 + c * 8;
            const size_t gx = (size_t)(m0 + r + l8) * 1024 + k0 + gro;
            const size_t gw = (size_t)(n0 + r + l8) * 1024 + k0 + gro;
            glds16(xh + gx, &Ah[r * 64]);
            glds16(xl + gx, &Al[r * 64]);
            glds16(wh + gw, &Bh[r * 64]);
            glds16(wl + gw, &Bl[r * 64]);
        }
        __syncthreads();  // staging visible

#pragma unroll
        for (int kc = 0; kc < 2; ++kc) {
            const int ch = (((kc * 4 + qd) ^ (i & 7)) << 3);
            short8 ah[8], al[8], bh2[2], bl2[2];
#pragma unroll
            for (int mm = 0; mm < 8; ++mm) {
                ah[mm] = *(const short8*)&Ah[(mm * 16 + i) * 64 + ch];
                al[mm] = *(const short8*)&Al[(mm * 16 + i) * 64 + ch];
            }
#pragma unroll
            for (int nn = 0; nn < 2; ++nn) {
                bh2[nn] = *(const short8*)&Bh[(nw + nn * 16 + i) * 64 + ch];
                bl2[nn] = *(const short8*)&Bl[(nw + nn * 16 + i) * 64 + ch];
            }
#pragma unroll
            for (int mm = 0; mm < 8; ++mm)
#pragma unroll
                for (int nn = 0; nn < 2; ++nn) {
                    acc[mm][nn] = __builtin_amdgcn_mfma_f32_16x16x32_bf16(
                        ah[mm], bh2[nn], acc[mm][nn], 0, 0, 0);
                    acc[mm][nn] = __builtin_amdgcn_mfma_f32_16x16x32_bf16(
                        al[mm], bh2[nn], acc[mm][nn], 0, 0, 0);
                    acc[mm][nn] = __builtin_amdgcn_mfma_f32_16x16x32_bf16(
                        ah[mm], bl2[nn], acc[mm][nn], 0, 0, 0);
                }
        }
    }

    // C layout: col = i (lane&15), row = qd*4 + reg  [m89-verified].
#pragma unroll
    for (int mm = 0; mm < 8; ++mm)
#pragma unroll
        for (int nn = 0; nn < 2; ++nn)
#pragma unroll
            for (int rr = 0; rr < 4; ++rr) {
                const int row = m0 + mm * 16 + qd * 4 + rr;  // token b*2048+s
                const int col = n0 + nw + nn * 16 + i;       // channel h*64+d
                const float v = acc[mm][nn][rr] + bias[col];
                Qf[(size_t)row * 1024 + col] = v;
                const unsigned short hs = f2bf(v);
                const float lo = v - bff(hs);
                const int b = row >> 11, s = row & 2047;
                const int hh = col >> 6, d = col & 63;
                const size_t oi = ((size_t)((b << 4) + hh) * 2048 + s) * 64 + d;
                Qb[oi] = hs;
                Qlo[oi] = f2bf(lo);
            }
}

// ---------------------------------------------------------------------------
// V-GEMM v2 (LDS-staged, pre-transposed output): A = Wvh [1024 ch, K],
// B = xh [4096 tok, K]; C[ch,tok] + bv[ch] -> Vt[b][ch][s].  1-term bf16.
// ---------------------------------------------------------------------------
__global__ __launch_bounds__(256, 1) void gemm_v(
    const unsigned short* __restrict__ wh, const unsigned short* __restrict__ xh,
    const float* __restrict__ bias, unsigned short* __restrict__ Vt)
{
    __shared__ unsigned short Ah[128 * 64];
    __shared__ unsigned short Bh[128 * 64];

    const int tid = threadIdx.x;
    const int w = tid >> 6, lane = tid & 63;
    const int i = lane & 15, qd = lane >> 4;
    const int l8 = lane >> 3, j = lane & 7;
    const int m0 = blockIdx.x * 128;           // channel tile
    const int n0 = blockIdx.y * 128;           // token tile
    const int nw = w * 32;

    f32x4 acc[8][2];
#pragma unroll
    for (int a = 0; a < 8; ++a)
#pragma unroll
        for (int b2 = 0; b2 < 2; ++b2) acc[a][b2] = f32x4{0.f, 0.f, 0.f, 0.f};

    for (int k0 = 0; k0 < 1024; k0 += 64) {
        __syncthreads();
        const int gro = ((j ^ l8) << 3);
#pragma unroll
        for (int c = 0; c < 4; ++c) {
            const int r = w * 32 + c * 8;
            glds16(wh + (size_t)(m0 + r + l8) * 1024 + k0 + gro, &Ah[r * 64]);
            glds16(xh + (size_t)(n0 + r + l8) * 1024 + k0 + gro, &Bh[r * 64]);
        }
        __syncthreads();

#pragma unroll
        for (int kc = 0; kc < 2; ++kc) {
            const int ch = (((kc * 4 + qd) ^ (i & 7)) << 3);
            short8 af[8], bf2[2];
#pragma unroll
            for (int mm = 0; mm < 8; ++mm)
                af[mm] = *(const short8*)&Ah[(mm * 16 + i) * 64 + ch];
#pragma unroll
            for (int nn = 0; nn < 2; ++nn)
                bf2[nn] = *(const short8*)&Bh[(nw + nn * 16 + i) * 64 + ch];
#pragma unroll
            for (int mm = 0; mm < 8; ++mm)
#pragma unroll
                for (int nn = 0; nn < 2; ++nn)
                    acc[mm][nn] = __builtin_amdgcn_mfma_f32_16x16x32_bf16(
                        af[mm], bf2[nn], acc[mm][nn], 0, 0, 0);
        }
    }

#pragma unroll
    for (int mm = 0; mm < 8; ++mm)
#pragma unroll
        for (int nn = 0; nn < 2; ++nn)
#pragma unroll
            for (int rr = 0; rr < 4; ++rr) {
                const int rch = m0 + mm * 16 + qd * 4 + rr;  // channel h*64+d
                const int tok = n0 + nw + nn * 16 + i;       // token b*2048+s
                const float v = acc[mm][nn][rr] + bias[rch];
                const int b = tok >> 11, s = tok & 2047;
                Vt[((size_t)(b * 1024 + rch)) * 2048 + s] = f2bf(v);
            }
}

// ---------------------------------------------------------------------------
// Buckets + row norms from fp32 q.  One thread per (token, head).
// ---------------------------------------------------------------------------
__global__ __launch_bounds__(256) void bucket_kernel(
    const float* __restrict__ Qf, const float* __restrict__ hp,
    int* __restrict__ buckets, float* __restrict__ rown)
{
    __shared__ float hpl[65 * 6];
    const int tid = threadIdx.x;
    if (tid < 65 * 6) hpl[tid] = hp[tid];
    __syncthreads();

    const int idx = blockIdx.x * 256 + tid;       // 65536 total
    const int m = idx >> 4, h = idx & 15;
    const float* qrow = Qf + (size_t)m * 1024 + h * 64;

    float pj[6];
    float nrm = 0.f;
#pragma unroll
    for (int n = 0; n < 6; ++n) pj[n] = hpl[64 * 6 + n];
    for (int d = 0; d < 64; ++d) {
        const float qv = qrow[d];
        nrm = fmaf(qv, qv, nrm);
#pragma unroll
        for (int n = 0; n < 6; ++n) pj[n] = fmaf(qv, hpl[d * 6 + n], pj[n]);
    }
    int bkt = 0;
#pragma unroll
    for (int n = 0; n < 6; ++n) bkt |= (pj[n] >= 0.f) << n;
    const int off = ((m >> 11) * 16 + h) * 2048 + (m & 2047);
    buckets[off] = bkt;
    rown[off] = nrm;
}

// ---------------------------------------------------------------------------
// Attention v3 (unchanged from round 4).  Grid (bh=32, qtile=16); 4 waves;
// wave owns 32 q-rows; key tile 64; LDS-staged Khi/Klo/V; fixed upper-bound
// softmax shift.  LDS 40 KB/block.
// ---------------------------------------------------------------------------
__global__ __launch_bounds__(256, 2) void attn_kernel(
    const unsigned short* __restrict__ Qb, const unsigned short* __restrict__ Qlo,
    const unsigned short* __restrict__ Vt, const int* __restrict__ bks,
    const float* __restrict__ rown, float* __restrict__ out)
{
    __shared__ unsigned short Khi[64 * 64];
    __shared__ unsigned short Klo[64 * 64];
    __shared__ unsigned short Vs[64 * 64];
    __shared__ unsigned short P[4][2][16 * 64];
    __shared__ float smax[4];

    const int tid = threadIdx.x;
    const int w = tid >> 6, lane = tid & 63;
    const int i = lane & 15, qd = lane >> 4;
    const int l8 = lane >> 3, j = lane & 7;
    const int bh = blockIdx.x;
    const int qbase = blockIdx.y * 128 + w * 32;

    const unsigned short* Qh = Qb + (size_t)bh * 2048 * 64;
    const unsigned short* Ql = Qlo + (size_t)bh * 2048 * 64;
    const unsigned short* Vb = Vt + (size_t)bh * 64 * 2048;
    const int* bk = bks + bh * 2048;
    const float* rnh = rown + bh * 2048;

    float lm = 0.f;
    for (int t = tid; t < 2048; t += 256) lm = fmaxf(lm, rnh[t]);
#pragma unroll
    for (int msk = 1; msk < 64; msk <<= 1) lm = fmaxf(lm, __shfl_xor(lm, msk));
    if (lane == 0) smax[w] = lm;
    __syncthreads();
    const float sqM = sqrtf(fmaxf(fmaxf(smax[0], smax[1]),
                                  fmaxf(smax[2], smax[3])));

    float mrow[2][4], lrun[2][4];
    int qbr[2][4];
#pragma unroll
    for (int ms = 0; ms < 2; ++ms)
#pragma unroll
        for (int r = 0; r < 4; ++r) {
            const int row = qbase + ms * 16 + qd * 4 + r;
            mrow[ms][r] = 1.96875f * sqrtf(rnh[row]) * sqM + 0.5f;
            qbr[ms][r] = bk[row];
            lrun[ms][r] = 0.f;
        }

    short8 aqh0[2], aqh1[2], aql0[2], aql1[2];
#pragma unroll
    for (int ms = 0; ms < 2; ++ms) {
        const unsigned short* qp = Qh + (size_t)(qbase + ms * 16 + i) * 64 + qd * 8;
        const unsigned short* lp = Ql + (size_t)(qbase + ms * 16 + i) * 64 + qd * 8;
        aqh0[ms] = *(const short8*)qp; aqh1[ms] = *(const short8*)(qp + 32);
        aql0[ms] = *(const short8*)lp; aql1[ms] = *(const short8*)(lp + 32);
    }

    f32x4 o[2][4];
#pragma unroll
    for (int ms = 0; ms < 2; ++ms)
#pragma unroll
        for (int d = 0; d < 4; ++d) o[ms][d] = f32x4{0.f, 0.f, 0.f, 0.f};

    for (int t0 = 0; t0 < 2048; t0 += 64) {
        __syncthreads();
#pragma unroll
        for (int c2 = 0; c2 < 2; ++c2) {
            const int r = w * 16 + c2 * 8 + l8;
            const int swz = ((j ^ l8) << 3);
            glds16(Qh + (size_t)(t0 + r) * 64 + swz, &Khi[w * 1024 + c2 * 512]);
            glds16(Ql + (size_t)(t0 + r) * 64 + swz, &Klo[w * 1024 + c2 * 512]);
            glds16(Vb + (size_t)r * 2048 + t0 + swz, &Vs[w * 1024 + c2 * 512]);
        }
        __syncthreads();

        f32x4 s[2][4];
        int kb[4];
#pragma unroll
        for (int sub = 0; sub < 4; ++sub) {
            const int kr = sub * 16 + i;
            const int sw = i & 7;
            const short8 bh0 = *(const short8*)&Khi[kr * 64 + ((qd ^ sw) << 3)];
            const short8 bh1 = *(const short8*)&Khi[kr * 64 + (((qd + 4) ^ sw) << 3)];
            const short8 bl0 = *(const short8*)&Klo[kr * 64 + ((qd ^ sw) << 3)];
            const short8 bl1 = *(const short8*)&Klo[kr * 64 + (((qd + 4) ^ sw) << 3)];
            kb[sub] = bk[t0 + kr];
#pragma unroll
            for (int ms = 0; ms < 2; ++ms) {
                f32x4 t = f32x4{0.f, 0.f, 0.f, 0.f};
                t = __builtin_amdgcn_mfma_f32_16x16x32_bf16(aqh0[ms], bh0, t, 0, 0, 0);
                t = __builtin_amdgcn_mfma_f32_16x16x32_bf16(aqh1[ms], bh1, t, 0, 0, 0);
                t = __builtin_amdgcn_mfma_f32_16x16x32_bf16(aql0[ms], bh0, t, 0, 0, 0);
                t = __builtin_amdgcn_mfma_f32_16x16x32_bf16(aql1[ms], bh1, t, 0, 0, 0);
                t = __builtin_amdgcn_mfma_f32_16x16x32_bf16(aqh0[ms], bl0, t, 0, 0, 0);
                t = __builtin_amdgcn_mfma_f32_16x16x32_bf16(aqh1[ms], bl1, t, 0, 0, 0);
                s[ms][sub] = t;
            }
        }

        short8 vb0[4], vb1[4];
#pragma unroll
        for (int dsub = 0; dsub < 4; ++dsub) {
            const int dr = dsub * 16 + i;
            const int sw = i & 7;
            vb0[dsub] = *(const short8*)&Vs[dr * 64 + ((qd ^ sw) << 3)];
            vb1[dsub] = *(const short8*)&Vs[dr * 64 + (((qd + 4) ^ sw) << 3)];
        }

#pragma unroll
        for (int ms = 0; ms < 2; ++ms) {
            unsigned short* Pw = &P[w][ms][0];
#pragma unroll
            for (int sub = 0; sub < 4; ++sub)
#pragma unroll
                for (int r = 0; r < 4; ++r) {
                    const float c = (kb[sub] == qbr[ms][r]) ? 1.96875f : 1.9375f;
                    const float p = __expf(fmaf(s[ms][sub][r], c, -mrow[ms][r]));
                    lrun[ms][r] += p;
                    const int row = qd * 4 + r, col = sub * 16 + i;
                    Pw[row * 64 + (((col >> 3) ^ (row & 7)) << 3) + (col & 7)] =
                        f2bf(p);
                }
            const short8 pa0 = *(const short8*)&Pw[i * 64 + ((qd ^ (i & 7)) << 3)];
            const short8 pa1 = *(const short8*)&Pw[i * 64 + (((qd + 4) ^ (i & 7)) << 3)];
#pragma unroll
            for (int dsub = 0; dsub < 4; ++dsub) {
                o[ms][dsub] = __builtin_amdgcn_mfma_f32_16x16x32_bf16(
                    pa0, vb0[dsub], o[ms][dsub], 0, 0, 0);
                o[ms][dsub] = __builtin_amdgcn_mfma_f32_16x16x32_bf16(
                    pa1, vb1[dsub], o[ms][dsub], 0, 0, 0);
            }
        }
    }

#pragma unroll
    for (int ms = 0; ms < 2; ++ms)
#pragma unroll
        for (int r = 0; r < 4; ++r) {
#pragma unroll
            for (int msk = 1; msk < 16; msk <<= 1)
                lrun[ms][r] += __shfl_xor(lrun[ms][r], msk);
        }
    const int b = bh >> 4, h = bh & 15;
#pragma unroll
    for (int ms = 0; ms < 2; ++ms)
#pragma unroll
        for (int dsub = 0; dsub < 4; ++dsub)
#pragma unroll
            for (int r = 0; r < 4; ++r) {
                const float v = o[ms][dsub][r] / lrun[ms][r];
                const int srow = qbase + ms * 16 + qd * 4 + r;
                out[((size_t)(b * 2048 + srow)) * 1024 + h * 64 + dsub * 16 + i] = v;
            }
}

// ---------------------------------------------------------------------------
extern "C" void kernel_launch(void* const* d_in, const int* in_sizes, int n_in,
                              void* d_out, int out_size, void* d_ws, size_t ws_size,
                              hipStream_t stream)
{
    const float* x  = (const float*)d_in[0];
    const float* Wq = (const float*)d_in[1];
    const float* bq = (const float*)d_in[2];
    const float* Wv = (const float*)d_in[3];
    const float* bv = (const float*)d_in[4];
    const float* hp = (const float*)d_in[5];
    float* out = (float*)d_out;

    char* ws = (char*)d_ws;
    const size_t MB = (size_t)1 << 20;
    unsigned short* xh  = (unsigned short*)(ws);            // 8 MB
    unsigned short* xl  = (unsigned short*)(ws + 8 * MB);   // 8 MB
    unsigned short* Wqh = (unsigned short*)(ws + 16 * MB);  // 2 MB
    unsigned short* Wql = (unsigned short*)(ws + 18 * MB);  // 2 MB
    unsigned short* Wvh = (unsigned short*)(ws + 20 * MB);  // 2 MB
    unsigned short* Qb  = (unsigned short*)(ws + 22 * MB);  // 8 MB
    unsigned short* Qlo = (unsigned short*)(ws + 30 * MB);  // 8 MB
    unsigned short* Vt  = (unsigned short*)(ws + 38 * MB);  // 8 MB
    float*          Qf  = (float*)(ws + 46 * MB);           // 16 MB
    int*        buckets = (int*)(ws + 62 * MB);             // 256 KB
    float*         rown = (float*)(ws + 62 * MB + 256 * 1024);  // 256 KB

    split_kernel<<<dim3(4096), 256, 0, stream>>>(x, xh, xl, 1048576);
    split_kernel<<<dim3(1024), 256, 0, stream>>>(Wq, Wqh, Wql, 262144);
    split_kernel<<<dim3(1024), 256, 0, stream>>>(Wv, Wvh, nullptr, 262144);

    gemm_q<<<dim3(32, 8), 256, 0, stream>>>(xh, xl, Wqh, Wql, bq, Qf, Qb, Qlo);
    gemm_v<<<dim3(8, 32), 256, 0, stream>>>(Wvh, xh, bv, Vt);
    bucket_kernel<<<dim3(256), 256, 0, stream>>>(Qf, hp, buckets, rown);
    attn_kernel<<<dim3(32, 16), 256, 0, stream>>>(Qb, Qlo, Vt, buckets, rown, out);
}

// Round 6
// 235.523 us; speedup vs baseline: 2.5062x; 1.0012x over previous
//
#include <hip/hip_runtime.h>

// ---------------------------------------------------------------------------
// LSH attention, MI355X.  B=2, S=2048, E=1024, H=16, Dh=64, NB=64, NH=6.
// ALL inputs/outputs are FP32.
//   0) split_kernel: fp32 -> bf16 hi (+ optional lo residual)
//   1) gemm_qv (MERGED, 512 blocks = 2/CU): blocks 0-255 compute
//      Q = x@Wq^T+bq (3-term hi/lo, -> Qf fp32 + Qb/Qlo bf16 [B,H,S,Dh]);
//      blocks 256-511 compute Vt = (x@Wv^T+bv)^T bf16 [B,H,Dh,S].
//      Both LDS-staged via global_load_lds(16B) + global-side XOR swizzle.
//   2) bucket_kernel: bucket bits = sign(fp32 q . hyperplanes) + row |q|^2
//   3) attn_kernel v4: grid (32 bh, 32 qtiles) = 1024 blocks = 4/CU (round-5
//      evidence: 512 blocks grid-capped occupancy at 20%).  Wave owns 16
//      q-rows; K-tile 64 LDS-staged; fixed upper-bound softmax shift; P
//      stored by TRUNCATION with lrun summing the same truncated weights
//      (self-consistent, saves 2 VALU ops/element on the 134M-element path).
// ---------------------------------------------------------------------------

typedef short short8 __attribute__((ext_vector_type(8)));
typedef float f32x4 __attribute__((ext_vector_type(4)));
typedef unsigned short us4 __attribute__((ext_vector_type(4)));

__device__ __forceinline__ float bff(unsigned short h) {
    return __uint_as_float(((unsigned int)h) << 16);
}
__device__ __forceinline__ unsigned short f2bf(float f) {  // RNE, finite inputs
    unsigned int u = __float_as_uint(f);
    u += 0x7fffu + ((u >> 16) & 1u);
    return (unsigned short)(u >> 16);
}

__device__ __forceinline__ void glds16(const unsigned short* g, unsigned short* l) {
    __builtin_amdgcn_global_load_lds(
        (const __attribute__((address_space(1))) unsigned int*)g,
        (__attribute__((address_space(3))) unsigned int*)l, 16, 0, 0);
}

// ---------------------------------------------------------------------------
__global__ __launch_bounds__(256) void split_kernel(
    const float* __restrict__ in, unsigned short* __restrict__ hi,
    unsigned short* __restrict__ lo, int n4)
{
    const int idx = blockIdx.x * 256 + threadIdx.x;
    if (idx >= n4) return;
    const float4 v = ((const float4*)in)[idx];
    us4 h;
    h.x = f2bf(v.x); h.y = f2bf(v.y); h.z = f2bf(v.z); h.w = f2bf(v.w);
    ((us4*)hi)[idx] = h;
    if (lo) {
        us4 l;
        l.x = f2bf(v.x - bff(h.x)); l.y = f2bf(v.y - bff(h.y));
        l.z = f2bf(v.z - bff(h.z)); l.w = f2bf(v.w - bff(h.w));
        ((us4*)lo)[idx] = l;
    }
}

// ---------------------------------------------------------------------------
// Merged projection GEMM.  512 blocks: b<256 -> Q path (m0=token-tile,
// n0=channel-tile); b>=256 -> V path (m0=channel-tile, n0=token-tile).
// 128x128 tile, BK=64, LDS staged with global-side XOR swizzle; fragment
// reads apply the inverse -> 2-way LDS conflicts only (free, m136).
// ---------------------------------------------------------------------------
__global__ __launch_bounds__(256, 1) void gemm_qv(
    const unsigned short* __restrict__ xh, const unsigned short* __restrict__ xl,
    const unsigned short* __restrict__ wqh, const unsigned short* __restrict__ wql,
    const unsigned short* __restrict__ wvh,
    const float* __restrict__ bq, const float* __restrict__ bv,
    float* __restrict__ Qf, unsigned short* __restrict__ Qb,
    unsigned short* __restrict__ Qlo, unsigned short* __restrict__ Vt)
{
    __shared__ unsigned short Ah[128 * 64], Al[128 * 64];
    __shared__ unsigned short Bh[128 * 64], Bl[128 * 64];

    const int tid = threadIdx.x;
    const int w = tid >> 6, lane = tid & 63;
    const int i = lane & 15, qd = lane >> 4;
    const int l8 = lane >> 3, j = lane & 7;
    const int nw = w * 32;
    const int blk = blockIdx.x;
    const bool isq = blk < 256;

    f32x4 acc[8][2];
#pragma unroll
    for (int a = 0; a < 8; ++a)
#pragma unroll
        for (int b2 = 0; b2 < 2; ++b2) acc[a][b2] = f32x4{0.f, 0.f, 0.f, 0.f};

    const int gro = ((j ^ l8) << 3);  // swizzled global chunk offset

    if (isq) {
        const int m0 = (blk >> 3) * 128;   // token tile
        const int n0 = (blk & 7) * 128;    // channel tile
        for (int k0 = 0; k0 < 1024; k0 += 64) {
            __syncthreads();
#pragma unroll
            for (int c = 0; c < 4; ++c) {
                const int r = w * 32 + c * 8;
                const size_t gx = (size_t)(m0 + r + l8) * 1024 + k0 + gro;
                const size_t gw = (size_t)(n0 + r + l8) * 1024 + k0 + gro;
                glds16(xh + gx, &Ah[r * 64]);
                glds16(xl + gx, &Al[r * 64]);
                glds16(wqh + gw, &Bh[r * 64]);
                glds16(wql + gw, &Bl[r * 64]);
            }
            __syncthreads();
#pragma unroll
            for (int kc = 0; kc < 2; ++kc) {
                const int ch = (((kc * 4 + qd) ^ (i & 7)) << 3);
                short8 ah[8], al[8], bh2[2], bl2[2];
#pragma unroll
                for (int mm = 0; mm < 8; ++mm) {
                    ah[mm] = *(const short8*)&Ah[(mm * 16 + i) * 64 + ch];
                    al[mm] = *(const short8*)&Al[(mm * 16 + i) * 64 + ch];
                }
#pragma unroll
                for (int nn = 0; nn < 2; ++nn) {
                    bh2[nn] = *(const short8*)&Bh[(nw + nn * 16 + i) * 64 + ch];
                    bl2[nn] = *(const short8*)&Bl[(nw + nn * 16 + i) * 64 + ch];
                }
#pragma unroll
                for (int mm = 0; mm < 8; ++mm)
#pragma unroll
                    for (int nn = 0; nn < 2; ++nn) {
                        acc[mm][nn] = __builtin_amdgcn_mfma_f32_16x16x32_bf16(
                            ah[mm], bh2[nn], acc[mm][nn], 0, 0, 0);
                        acc[mm][nn] = __builtin_amdgcn_mfma_f32_16x16x32_bf16(
                            al[mm], bh2[nn], acc[mm][nn], 0, 0, 0);
                        acc[mm][nn] = __builtin_amdgcn_mfma_f32_16x16x32_bf16(
                            ah[mm], bl2[nn], acc[mm][nn], 0, 0, 0);
                    }
            }
        }
        // epilogue: C layout col=i, row=qd*4+reg [m89]
#pragma unroll
        for (int mm = 0; mm < 8; ++mm)
#pragma unroll
            for (int nn = 0; nn < 2; ++nn)
#pragma unroll
                for (int rr = 0; rr < 4; ++rr) {
                    const int row = m0 + mm * 16 + qd * 4 + rr;  // token
                    const int col = n0 + nw + nn * 16 + i;       // channel
                    const float v = acc[mm][nn][rr] + bq[col];
                    Qf[(size_t)row * 1024 + col] = v;
                    const unsigned short hs = f2bf(v);
                    const float lo = v - bff(hs);
                    const int b = row >> 11, s = row & 2047;
                    const int hh = col >> 6, d = col & 63;
                    const size_t oi = ((size_t)((b << 4) + hh) * 2048 + s) * 64 + d;
                    Qb[oi] = hs;
                    Qlo[oi] = f2bf(lo);
                }
    } else {
        const int b2 = blk - 256;
        const int m0 = (b2 & 7) * 128;     // channel tile
        const int n0 = (b2 >> 3) * 128;    // token tile
        for (int k0 = 0; k0 < 1024; k0 += 64) {
            __syncthreads();
#pragma unroll
            for (int c = 0; c < 4; ++c) {
                const int r = w * 32 + c * 8;
                glds16(wvh + (size_t)(m0 + r + l8) * 1024 + k0 + gro, &Ah[r * 64]);
                glds16(xh + (size_t)(n0 + r + l8) * 1024 + k0 + gro, &Bh[r * 64]);
            }
            __syncthreads();
#pragma unroll
            for (int kc = 0; kc < 2; ++kc) {
                const int ch = (((kc * 4 + qd) ^ (i & 7)) << 3);
                short8 af[8], bf2[2];
#pragma unroll
                for (int mm = 0; mm < 8; ++mm)
                    af[mm] = *(const short8*)&Ah[(mm * 16 + i) * 64 + ch];
#pragma unroll
                for (int nn = 0; nn < 2; ++nn)
                    bf2[nn] = *(const short8*)&Bh[(nw + nn * 16 + i) * 64 + ch];
#pragma unroll
                for (int mm = 0; mm < 8; ++mm)
#pragma unroll
                    for (int nn = 0; nn < 2; ++nn)
                        acc[mm][nn] = __builtin_amdgcn_mfma_f32_16x16x32_bf16(
                            af[mm], bf2[nn], acc[mm][nn], 0, 0, 0);
            }
        }
#pragma unroll
        for (int mm = 0; mm < 8; ++mm)
#pragma unroll
            for (int nn = 0; nn < 2; ++nn)
#pragma unroll
                for (int rr = 0; rr < 4; ++rr) {
                    const int rch = m0 + mm * 16 + qd * 4 + rr;  // channel
                    const int tok = n0 + nw + nn * 16 + i;       // token
                    const float v = acc[mm][nn][rr] + bv[rch];
                    const int b = tok >> 11, s = tok & 2047;
                    Vt[((size_t)(b * 1024 + rch)) * 2048 + s] = f2bf(v);
                }
    }
}

// ---------------------------------------------------------------------------
// Buckets + row norms from fp32 q.  One thread per (token, head).
// ---------------------------------------------------------------------------
__global__ __launch_bounds__(256) void bucket_kernel(
    const float* __restrict__ Qf, const float* __restrict__ hp,
    int* __restrict__ buckets, float* __restrict__ rown)
{
    __shared__ float hpl[65 * 6];
    const int tid = threadIdx.x;
    if (tid < 65 * 6) hpl[tid] = hp[tid];
    __syncthreads();

    const int idx = blockIdx.x * 256 + tid;       // 65536 total
    const int m = idx >> 4, h = idx & 15;
    const float* qrow = Qf + (size_t)m * 1024 + h * 64;

    float pj[6];
    float nrm = 0.f;
#pragma unroll
    for (int n = 0; n < 6; ++n) pj[n] = hpl[64 * 6 + n];
    for (int d = 0; d < 64; ++d) {
        const float qv = qrow[d];
        nrm = fmaf(qv, qv, nrm);
#pragma unroll
        for (int n = 0; n < 6; ++n) pj[n] = fmaf(qv, hpl[d * 6 + n], pj[n]);
    }
    int bkt = 0;
#pragma unroll
    for (int n = 0; n < 6; ++n) bkt |= (pj[n] >= 0.f) << n;
    const int off = ((m >> 11) * 16 + h) * 2048 + (m & 2047);
    buckets[off] = bkt;
    rown[off] = nrm;
}

// ---------------------------------------------------------------------------
// Attention v4.  Grid (bh=32, qtile=32) = 1024 blocks = 4/CU; 4 waves; wave
// owns 16 q-rows; K-tile 64 LDS-staged (Khi/Klo/Vs 24 KB + P 8 KB = 32 KB).
// Fixed upper-bound softmax shift; truncation-consistent P/lrun.
// ---------------------------------------------------------------------------
__global__ __launch_bounds__(256, 4) void attn_kernel(
    const unsigned short* __restrict__ Qb, const unsigned short* __restrict__ Qlo,
    const unsigned short* __restrict__ Vt, const int* __restrict__ bks,
    const float* __restrict__ rown, float* __restrict__ out)
{
    __shared__ unsigned short Khi[64 * 64];
    __shared__ unsigned short Klo[64 * 64];
    __shared__ unsigned short Vs[64 * 64];
    __shared__ unsigned short P[4][16 * 64];
    __shared__ float smax[4];

    const int tid = threadIdx.x;
    const int w = tid >> 6, lane = tid & 63;
    const int i = lane & 15, qd = lane >> 4;
    const int l8 = lane >> 3, j = lane & 7;
    const int bh = blockIdx.x;
    const int q0 = blockIdx.y * 64 + w * 16;

    const unsigned short* Qh = Qb + (size_t)bh * 2048 * 64;
    const unsigned short* Ql = Qlo + (size_t)bh * 2048 * 64;
    const unsigned short* Vb = Vt + (size_t)bh * 64 * 2048;
    const int* bk = bks + bh * 2048;
    const float* rnh = rown + bh * 2048;
    unsigned short* Pw = &P[w][0];

    // prologue: per-(b,h) max key norm -> fixed per-row logit upper bound
    float lm = 0.f;
    for (int t = tid; t < 2048; t += 256) lm = fmaxf(lm, rnh[t]);
#pragma unroll
    for (int msk = 1; msk < 64; msk <<= 1) lm = fmaxf(lm, __shfl_xor(lm, msk));
    if (lane == 0) smax[w] = lm;
    __syncthreads();
    const float sqM = sqrtf(fmaxf(fmaxf(smax[0], smax[1]),
                                  fmaxf(smax[2], smax[3])));

    float mrow[4], lrun[4];
    int qbr[4];
#pragma unroll
    for (int r = 0; r < 4; ++r) {
        const int row = q0 + qd * 4 + r;
        mrow[r] = 1.96875f * sqrtf(rnh[row]) * sqM + 0.5f;  // >= any logit
        qbr[r] = bk[row];
        lrun[r] = 0.f;
    }

    const unsigned short* qp = Qh + (size_t)(q0 + i) * 64 + qd * 8;
    const unsigned short* lp = Ql + (size_t)(q0 + i) * 64 + qd * 8;
    const short8 aqh0 = *(const short8*)qp, aqh1 = *(const short8*)(qp + 32);
    const short8 aql0 = *(const short8*)lp, aql1 = *(const short8*)(lp + 32);

    f32x4 o[4];
#pragma unroll
    for (int d = 0; d < 4; ++d) o[d] = f32x4{0.f, 0.f, 0.f, 0.f};

    for (int t0 = 0; t0 < 2048; t0 += 64) {
        __syncthreads();
#pragma unroll
        for (int c2 = 0; c2 < 2; ++c2) {
            const int r = w * 16 + c2 * 8 + l8;
            const int swz = ((j ^ l8) << 3);
            glds16(Qh + (size_t)(t0 + r) * 64 + swz, &Khi[w * 1024 + c2 * 512]);
            glds16(Ql + (size_t)(t0 + r) * 64 + swz, &Klo[w * 1024 + c2 * 512]);
            glds16(Vb + (size_t)r * 2048 + t0 + swz, &Vs[w * 1024 + c2 * 512]);
        }
        __syncthreads();

        f32x4 s[4];
        int kb[4];
#pragma unroll
        for (int sub = 0; sub < 4; ++sub) {
            const int kr = sub * 16 + i;
            const int sw = i & 7;
            const short8 bh0 = *(const short8*)&Khi[kr * 64 + ((qd ^ sw) << 3)];
            const short8 bh1 = *(const short8*)&Khi[kr * 64 + (((qd + 4) ^ sw) << 3)];
            const short8 bl0 = *(const short8*)&Klo[kr * 64 + ((qd ^ sw) << 3)];
            const short8 bl1 = *(const short8*)&Klo[kr * 64 + (((qd + 4) ^ sw) << 3)];
            kb[sub] = bk[t0 + kr];
            f32x4 t = f32x4{0.f, 0.f, 0.f, 0.f};
            t = __builtin_amdgcn_mfma_f32_16x16x32_bf16(aqh0, bh0, t, 0, 0, 0);
            t = __builtin_amdgcn_mfma_f32_16x16x32_bf16(aqh1, bh1, t, 0, 0, 0);
            t = __builtin_amdgcn_mfma_f32_16x16x32_bf16(aql0, bh0, t, 0, 0, 0);
            t = __builtin_amdgcn_mfma_f32_16x16x32_bf16(aql1, bh1, t, 0, 0, 0);
            t = __builtin_amdgcn_mfma_f32_16x16x32_bf16(aqh0, bl0, t, 0, 0, 0);
            t = __builtin_amdgcn_mfma_f32_16x16x32_bf16(aqh1, bl1, t, 0, 0, 0);
            s[sub] = t;
        }

        short8 vb0[4], vb1[4];
#pragma unroll
        for (int dsub = 0; dsub < 4; ++dsub) {
            const int dr = dsub * 16 + i;
            const int sw = i & 7;
            vb0[dsub] = *(const short8*)&Vs[dr * 64 + ((qd ^ sw) << 3)];
            vb1[dsub] = *(const short8*)&Vs[dr * 64 + (((qd + 4) ^ sw) << 3)];
        }

        // exp with fixed shift; TRUNCATED weights, self-consistent with lrun
#pragma unroll
        for (int sub = 0; sub < 4; ++sub)
#pragma unroll
            for (int r = 0; r < 4; ++r) {
                const float c = (kb[sub] == qbr[r]) ? 1.96875f : 1.9375f;
                const float p = __expf(fmaf(s[sub][r], c, -mrow[r]));
                const unsigned int pu = __float_as_uint(p);
                lrun[r] += __uint_as_float(pu & 0xffff0000u);
                const int row = qd * 4 + r, col = sub * 16 + i;
                Pw[row * 64 + (((col >> 3) ^ (row & 7)) << 3) + (col & 7)] =
                    (unsigned short)(pu >> 16);
            }
        const short8 pa0 = *(const short8*)&Pw[i * 64 + ((qd ^ (i & 7)) << 3)];
        const short8 pa1 = *(const short8*)&Pw[i * 64 + (((qd + 4) ^ (i & 7)) << 3)];

#pragma unroll
        for (int dsub = 0; dsub < 4; ++dsub) {
            o[dsub] = __builtin_amdgcn_mfma_f32_16x16x32_bf16(pa0, vb0[dsub], o[dsub], 0, 0, 0);
            o[dsub] = __builtin_amdgcn_mfma_f32_16x16x32_bf16(pa1, vb1[dsub], o[dsub], 0, 0, 0);
        }
    }

    // epilogue: reduce row sums over the 16-lane col groups, write fp32
#pragma unroll
    for (int r = 0; r < 4; ++r) {
#pragma unroll
        for (int msk = 1; msk < 16; msk <<= 1)
            lrun[r] += __shfl_xor(lrun[r], msk);
    }
    const int b = bh >> 4, h = bh & 15;
#pragma unroll
    for (int dsub = 0; dsub < 4; ++dsub)
#pragma unroll
        for (int r = 0; r < 4; ++r) {
            const float v = o[dsub][r] / lrun[r];
            const int srow = q0 + qd * 4 + r;
            out[((size_t)(b * 2048 + srow)) * 1024 + h * 64 + dsub * 16 + i] = v;
        }
}

// ---------------------------------------------------------------------------
extern "C" void kernel_launch(void* const* d_in, const int* in_sizes, int n_in,
                              void* d_out, int out_size, void* d_ws, size_t ws_size,
                              hipStream_t stream)
{
    const float* x  = (const float*)d_in[0];
    const float* Wq = (const float*)d_in[1];
    const float* bq = (const float*)d_in[2];
    const float* Wv = (const float*)d_in[3];
    const float* bv = (const float*)d_in[4];
    const float* hp = (const float*)d_in[5];
    float* out = (float*)d_out;

    char* ws = (char*)d_ws;
    const size_t MB = (size_t)1 << 20;
    unsigned short* xh  = (unsigned short*)(ws);            // 8 MB
    unsigned short* xl  = (unsigned short*)(ws + 8 * MB);   // 8 MB
    unsigned short* Wqh = (unsigned short*)(ws + 16 * MB);  // 2 MB
    unsigned short* Wql = (unsigned short*)(ws + 18 * MB);  // 2 MB
    unsigned short* Wvh = (unsigned short*)(ws + 20 * MB);  // 2 MB
    unsigned short* Qb  = (unsigned short*)(ws + 22 * MB);  // 8 MB
    unsigned short* Qlo = (unsigned short*)(ws + 30 * MB);  // 8 MB
    unsigned short* Vt  = (unsigned short*)(ws + 38 * MB);  // 8 MB
    float*          Qf  = (float*)(ws + 46 * MB);           // 16 MB
    int*        buckets = (int*)(ws + 62 * MB);             // 256 KB
    float*         rown = (float*)(ws + 62 * MB + 256 * 1024);  // 256 KB

    split_kernel<<<dim3(4096), 256, 0, stream>>>(x, xh, xl, 1048576);
    split_kernel<<<dim3(1024), 256, 0, stream>>>(Wq, Wqh, Wql, 262144);
    split_kernel<<<dim3(1024), 256, 0, stream>>>(Wv, Wvh, nullptr, 262144);

    gemm_qv<<<dim3(512), 256, 0, stream>>>(xh, xl, Wqh, Wql, Wvh, bq, bv,
                                           Qf, Qb, Qlo, Vt);
    bucket_kernel<<<dim3(256), 256, 0, stream>>>(Qf, hp, buckets, rown);
    attn_kernel<<<dim3(32, 32), 256, 0, stream>>>(Qb, Qlo, Vt, buckets, rown, out);
}